// Round 21
// baseline (108.608 us; speedup 1.0000x reference)
//
#include <hip/hip_runtime.h>
#include <hip/hip_bf16.h>

typedef __attribute__((ext_vector_type(8))) short bf16x8;
typedef __attribute__((ext_vector_type(4))) float f32x4;

__device__ __forceinline__ short f2b(float f) {
    __hip_bfloat16 h = __float2bfloat16(f);   // RNE
    return __builtin_bit_cast(short, h);
}

#define NPH 32
#define KC  128     // floats per row per phase (512 B f32)

// Kernel 1 (rewritten): one launch, two roles.
//   blocks 0..255: x f32 -> bf16 (one float4/thread, 65536 total).
//   blocks 256..259: y2 = 2*(x @ A^T) as bf16 via MFMA -- replaces the old
//     4096-wave serial-dot part B (128 MB cached reads, ~4 us) with a
//     33-MFLOP MFMA tile job (~2 MB, ~1 us). Block bt: tokens bt*16..+15;
//     wave v: r-cols v*16..+15; K-loop 128 x 16x16x32 bf16.
__global__ void __launch_bounds__(256)
prep_kernel(const float* __restrict__ x,
            const float* __restrict__ A,
            ushort* __restrict__ xb,     // [64][4096] bf16
            ushort* __restrict__ yb) {   // [64][64] bf16
    const int tid = threadIdx.x, bid = blockIdx.x;

    if (bid < 256) {
        const int gid = bid * 256 + tid;
        float4 v = ((const float4*)x)[gid];
        ushort4 s;
        s.x = (ushort)f2b(v.x); s.y = (ushort)f2b(v.y);
        s.z = (ushort)f2b(v.z); s.w = (ushort)f2b(v.w);
        ((ushort4*)xb)[gid] = s;
        return;
    }

    // ---- y2 MFMA blocks ----
    const int bt   = bid - 256;              // 0..3 -> tokens bt*16..+15
    const int wv   = tid >> 6;               // 0..3 -> r-cols wv*16..+15
    const int lane = tid & 63;
    const int c    = lane & 15;
    const int kg   = lane >> 4;

    const float* xr = x + (size_t)(bt * 16 + c) * 4096 + kg * 8;
    const float* ar = A + (size_t)(wv * 16 + c) * 4096 + kg * 8;

    f32x4 acc = {0.f, 0.f, 0.f, 0.f};
    for (int k = 0; k < 4096; k += 32) {
        f32x4 a0 = *(const f32x4*)(xr + k);
        f32x4 a1 = *(const f32x4*)(xr + k + 4);
        f32x4 b0 = *(const f32x4*)(ar + k);
        f32x4 b1 = *(const f32x4*)(ar + k + 4);
        bf16x8 aa, bb;
        aa[0] = f2b(a0[0]); aa[1] = f2b(a0[1]); aa[2] = f2b(a0[2]); aa[3] = f2b(a0[3]);
        aa[4] = f2b(a1[0]); aa[5] = f2b(a1[1]); aa[6] = f2b(a1[2]); aa[7] = f2b(a1[3]);
        bb[0] = f2b(b0[0]); bb[1] = f2b(b0[1]); bb[2] = f2b(b0[2]); bb[3] = f2b(b0[3]);
        bb[4] = f2b(b1[0]); bb[5] = f2b(b1[1]); bb[6] = f2b(b1[2]); bb[7] = f2b(b1[3]);
        acc = __builtin_amdgcn_mfma_f32_16x16x32_bf16(aa, bb, acc, 0, 0, 0);
    }
    // C layout: token = bt*16 + kg*4 + r, rcol = wv*16 + c
    #pragma unroll
    for (int r = 0; r < 4; ++r)
        yb[(size_t)(bt * 16 + kg * 4 + r) * 64 + wv * 16 + c]
            = (ushort)f2b(2.0f * acc[r]);
}

// Kernel 2: out[64][16384] = x@W^T + y2@B^T.  (EXACT R17 kernel -- proven
// 58.6 us: 1 block/CU, quad-buffer depth-3, counted vmcnt(16), k-rotation.)
__global__ void __launch_bounds__(512)
lora_gemm(const float* __restrict__ W,      // [16384][4096]
          const float* __restrict__ Bm,     // [16384][64]
          const ushort* __restrict__ xb,    // [64][4096] bf16
          const ushort* __restrict__ yb,    // [64][64] bf16
          float* __restrict__ out) {        // [64][16384]
    __shared__ char buf[4][64 * 512];       // 4 x 32 KB f32 panels

    const int tid  = threadIdx.x;
    const int w    = tid >> 6;              // wave 0..7
    const int lane = tid & 63;
    const int j0   = blockIdx.x << 6;       // 64 W-rows / out-cols per block
    const int p0   = blockIdx.x & 31;       // phase rotation start

    if (w >= 4) {
        // ------- STREAMER (waves 4..7): rows s*16 .. s*16+15 -------------
        const int s = w - 4;
        // issue slot i: stages phase (p0+i)&31 into buf[i&3].
        auto issue = [&](int i) {
            const int p = (p0 + i) & 31;
            char* dst = &buf[i & 3][0];
            #pragma unroll
            for (int k = 0; k < 8; ++k) {
                const int qa = s * 16 + k * 2;          // first of 2 rows
                const int q  = qa + (lane >> 5);        // this lane's row
                const int b  = (lane & 31) * 16;        // byte in 512B chunk
                const char* src = (const char*)(W + (size_t)(j0 + q) * 4096
                                                + (size_t)p * KC)
                                  + (b ^ ((q & 7) << 4));   // inverse swz
                __builtin_amdgcn_global_load_lds(
                    (const uint32_t*)src,
                    (uint32_t*)(dst + qa * 512), 16, 0, 0);
            }
        };

        issue(0);
        issue(1);
        issue(2);
        for (int i = 0; i < NPH - 2; ++i) {
            // slot i landed; i+1, i+2 stay in flight (16 outstanding)
            asm volatile("s_waitcnt vmcnt(16)" ::: "memory");
            __builtin_amdgcn_s_barrier();
            if (i + 3 < NPH) issue(i + 3);   // depth-3: 24 in flight
        }
        asm volatile("s_waitcnt vmcnt(8)" ::: "memory");   // i = NPH-2
        __builtin_amdgcn_s_barrier();
        asm volatile("s_waitcnt vmcnt(0)" ::: "memory");   // i = NPH-1
        __builtin_amdgcn_s_barrier();
        return;
    }

    // ------- CONSUMER (waves 0..3): tokens w*16..w*16+15 -----------------
    const int c  = lane & 15;               // token row / D-col index
    const int kg = lane >> 4;               // k-group, offset kg*8
    const ushort* xrow = xb + (size_t)(w * 16 + c) * 4096 + kg * 8;

    f32x4 acc[4];
    #pragma unroll
    for (int n = 0; n < 4; ++n) acc[n] = f32x4{0.f, 0.f, 0.f, 0.f};

    for (int i = 0; i < NPH; ++i) {
        const int p = (p0 + i) & 31;
        __builtin_amdgcn_s_barrier();       // B_i: buf[i&3] ready
        const char* lb = &buf[i & 3][0];
        #pragma unroll
        for (int sl = 0; sl < 4; ++sl) {
            bf16x8 aa = *(const bf16x8*)(xrow + p * KC + sl * 32);
            #pragma unroll
            for (int n = 0; n < 4; ++n) {
                const int q   = n * 16 + c; // W-row within block = D col
                const int swz = (q & 7) << 4;
                const char* base = lb + q * 512;
                f32x4 w0 = *(const f32x4*)(base + ((sl * 128 + kg * 32) ^ swz));
                f32x4 w1 = *(const f32x4*)(base + ((sl * 128 + kg * 32 + 16) ^ swz));
                bf16x8 bb;
                bb[0] = f2b(w0[0]); bb[1] = f2b(w0[1]);
                bb[2] = f2b(w0[2]); bb[3] = f2b(w0[3]);
                bb[4] = f2b(w1[0]); bb[5] = f2b(w1[1]);
                bb[6] = f2b(w1[2]); bb[7] = f2b(w1[3]);
                acc[n] = __builtin_amdgcn_mfma_f32_16x16x32_bf16(
                    aa, bb, acc[n], 0, 0, 0);
            }
        }
    }

    // lora tail: 2 K-steps over r=64 per col-subtile
    {
        const ushort* y0 = yb + (size_t)(w * 16 + c) * 64 + kg * 8;
        #pragma unroll
        for (int n = 0; n < 4; ++n) {
            const float* br = Bm + (size_t)(j0 + n * 16 + c) * 64 + kg * 8;
            #pragma unroll
            for (int k = 0; k < 64; k += 32) {
                f32x4 w0 = *(const f32x4*)(br + k);
                f32x4 w1 = *(const f32x4*)(br + k + 4);
                bf16x8 bb;
                bb[0] = f2b(w0[0]); bb[1] = f2b(w0[1]);
                bb[2] = f2b(w0[2]); bb[3] = f2b(w0[3]);
                bb[4] = f2b(w1[0]); bb[5] = f2b(w1[1]);
                bb[6] = f2b(w1[2]); bb[7] = f2b(w1[3]);
                bf16x8 aa = *(const bf16x8*)(y0 + k);
                acc[n] = __builtin_amdgcn_mfma_f32_16x16x32_bf16(
                    aa, bb, acc[n], 0, 0, 0);
            }
        }
    }

    // store: token row = w*16 + kg*4 + r, col = j0 + n*16 + c
    #pragma unroll
    for (int n = 0; n < 4; ++n) {
        float* op = out + j0 + n * 16 + c;
        #pragma unroll
        for (int r = 0; r < 4; ++r)
            op[(size_t)(w * 16 + kg * 4 + r) * 16384] = acc[n][r];
    }
}

extern "C" void kernel_launch(void* const* d_in, const int* in_sizes, int n_in,
                              void* d_out, int out_size, void* d_ws, size_t ws_size,
                              hipStream_t stream) {
    const float* x  = (const float*)d_in[0];
    const float* W  = (const float*)d_in[1];
    const float* A  = (const float*)d_in[2];
    const float* Bm = (const float*)d_in[3];
    float* out = (float*)d_out;

    ushort* xb = (ushort*)d_ws;                          // 64*4096*2 = 524288 B
    ushort* yb = (ushort*)((char*)d_ws + 524288);        // 64*64*2   = 8192 B

    prep_kernel<<<260, 256, 0, stream>>>(x, A, xb, yb);
    lora_gemm<<<256, 512, 0, stream>>>(W, Bm, xb, yb, out);
}

// Round 22
// 58.874 us; speedup vs baseline: 1.8448x; 1.8448x over previous
//
#include <hip/hip_runtime.h>
#include <hip/hip_bf16.h>

typedef __attribute__((ext_vector_type(8))) short bf16x8;
typedef __attribute__((ext_vector_type(4))) float f32x4;

__device__ __forceinline__ short f2b(float f) {
    __hip_bfloat16 h = __float2bfloat16(f);   // RNE
    return __builtin_bit_cast(short, h);
}

#define NPH 32
#define KC  128     // floats per row per phase (512 B f32)

// Kernel 1: x f32 -> bf16, and y2 = 2*(x @ A^T) as bf16.  (original proven
// form: part B is latency-hidden by TLP -- 4096 parallel waves, each with 16
// independent loads + shuffle reduce. R21's 4-block serial-MFMA replacement
// was a 50 us latency chain; reverted.)
__global__ void prep_kernel(const float* __restrict__ x,
                            const float* __restrict__ A,
                            ushort* __restrict__ xb,     // [64][4096] bf16
                            ushort* __restrict__ yb) {   // [64][64] bf16
    const int tid = threadIdx.x, bid = blockIdx.x;

    const int gid = bid * 256 + tid;
    if (gid < 65536) {
        float4 v = ((const float4*)x)[gid];
        ushort4 s;
        s.x = (ushort)f2b(v.x); s.y = (ushort)f2b(v.y);
        s.z = (ushort)f2b(v.z); s.w = (ushort)f2b(v.w);
        ((ushort4*)xb)[gid] = s;
    }

    const int wave = tid >> 6, lane = tid & 63;
    const int idx = bid * 4 + wave;          // 0..4095
    const int t = idx >> 6, r = idx & 63;
    const float4* xr = (const float4*)(x + (size_t)t * 4096);
    const float4* ar = (const float4*)(A + (size_t)r * 4096);
    float s = 0.f;
    #pragma unroll
    for (int i = 0; i < 16; ++i) {
        float4 a = xr[i * 64 + lane];
        float4 b = ar[i * 64 + lane];
        s += a.x * b.x + a.y * b.y + a.z * b.z + a.w * b.w;
    }
    #pragma unroll
    for (int off = 32; off; off >>= 1) s += __shfl_xor(s, off, 64);
    if (lane == 0) yb[idx] = (ushort)f2b(2.0f * s);
}

// Kernel 2: out[64][16384] = x@W^T + y2@B^T.  (EXACT R17 kernel -- proven
// 58.6 us: 256 blocks x 512 thr, 1 block/CU, quad-buffer gload_lds depth-3,
// counted vmcnt(16), per-block k-phase rotation, pre-swizzled source.)
__global__ void __launch_bounds__(512)
lora_gemm(const float* __restrict__ W,      // [16384][4096]
          const float* __restrict__ Bm,     // [16384][64]
          const ushort* __restrict__ xb,    // [64][4096] bf16
          const ushort* __restrict__ yb,    // [64][64] bf16
          float* __restrict__ out) {        // [64][16384]
    __shared__ char buf[4][64 * 512];       // 4 x 32 KB f32 panels

    const int tid  = threadIdx.x;
    const int w    = tid >> 6;              // wave 0..7
    const int lane = tid & 63;
    const int j0   = blockIdx.x << 6;       // 64 W-rows / out-cols per block
    const int p0   = blockIdx.x & 31;       // phase rotation start

    if (w >= 4) {
        // ------- STREAMER (waves 4..7): rows s*16 .. s*16+15 -------------
        const int s = w - 4;
        // issue slot i: stages phase (p0+i)&31 into buf[i&3].
        auto issue = [&](int i) {
            const int p = (p0 + i) & 31;
            char* dst = &buf[i & 3][0];
            #pragma unroll
            for (int k = 0; k < 8; ++k) {
                const int qa = s * 16 + k * 2;          // first of 2 rows
                const int q  = qa + (lane >> 5);        // this lane's row
                const int b  = (lane & 31) * 16;        // byte in 512B chunk
                const char* src = (const char*)(W + (size_t)(j0 + q) * 4096
                                                + (size_t)p * KC)
                                  + (b ^ ((q & 7) << 4));   // inverse swz
                __builtin_amdgcn_global_load_lds(
                    (const uint32_t*)src,
                    (uint32_t*)(dst + qa * 512), 16, 0, 0);
            }
        };

        issue(0);
        issue(1);
        issue(2);
        for (int i = 0; i < NPH - 2; ++i) {
            // slot i landed; i+1, i+2 stay in flight (16 outstanding)
            asm volatile("s_waitcnt vmcnt(16)" ::: "memory");
            __builtin_amdgcn_s_barrier();
            if (i + 3 < NPH) issue(i + 3);   // depth-3: 24 in flight
        }
        asm volatile("s_waitcnt vmcnt(8)" ::: "memory");   // i = NPH-2
        __builtin_amdgcn_s_barrier();
        asm volatile("s_waitcnt vmcnt(0)" ::: "memory");   // i = NPH-1
        __builtin_amdgcn_s_barrier();
        return;
    }

    // ------- CONSUMER (waves 0..3): tokens w*16..w*16+15 -----------------
    const int c  = lane & 15;               // token row / D-col index
    const int kg = lane >> 4;               // k-group, offset kg*8
    const ushort* xrow = xb + (size_t)(w * 16 + c) * 4096 + kg * 8;

    f32x4 acc[4];
    #pragma unroll
    for (int n = 0; n < 4; ++n) acc[n] = f32x4{0.f, 0.f, 0.f, 0.f};

    for (int i = 0; i < NPH; ++i) {
        const int p = (p0 + i) & 31;
        __builtin_amdgcn_s_barrier();       // B_i: buf[i&3] ready
        const char* lb = &buf[i & 3][0];
        #pragma unroll
        for (int sl = 0; sl < 4; ++sl) {
            bf16x8 aa = *(const bf16x8*)(xrow + p * KC + sl * 32);
            #pragma unroll
            for (int n = 0; n < 4; ++n) {
                const int q   = n * 16 + c; // W-row within block = D col
                const int swz = (q & 7) << 4;
                const char* base = lb + q * 512;
                f32x4 w0 = *(const f32x4*)(base + ((sl * 128 + kg * 32) ^ swz));
                f32x4 w1 = *(const f32x4*)(base + ((sl * 128 + kg * 32 + 16) ^ swz));
                bf16x8 bb;
                bb[0] = f2b(w0[0]); bb[1] = f2b(w0[1]);
                bb[2] = f2b(w0[2]); bb[3] = f2b(w0[3]);
                bb[4] = f2b(w1[0]); bb[5] = f2b(w1[1]);
                bb[6] = f2b(w1[2]); bb[7] = f2b(w1[3]);
                acc[n] = __builtin_amdgcn_mfma_f32_16x16x32_bf16(
                    aa, bb, acc[n], 0, 0, 0);
            }
        }
    }

    // lora tail: 2 K-steps over r=64 per col-subtile
    {
        const ushort* y0 = yb + (size_t)(w * 16 + c) * 64 + kg * 8;
        #pragma unroll
        for (int n = 0; n < 4; ++n) {
            const float* br = Bm + (size_t)(j0 + n * 16 + c) * 64 + kg * 8;
            #pragma unroll
            for (int k = 0; k < 64; k += 32) {
                f32x4 w0 = *(const f32x4*)(br + k);
                f32x4 w1 = *(const f32x4*)(br + k + 4);
                bf16x8 bb;
                bb[0] = f2b(w0[0]); bb[1] = f2b(w0[1]);
                bb[2] = f2b(w0[2]); bb[3] = f2b(w0[3]);
                bb[4] = f2b(w1[0]); bb[5] = f2b(w1[1]);
                bb[6] = f2b(w1[2]); bb[7] = f2b(w1[3]);
                bf16x8 aa = *(const bf16x8*)(y0 + k);
                acc[n] = __builtin_amdgcn_mfma_f32_16x16x32_bf16(
                    aa, bb, acc[n], 0, 0, 0);
            }
        }
    }

    // store: token row = w*16 + kg*4 + r, col = j0 + n*16 + c
    #pragma unroll
    for (int n = 0; n < 4; ++n) {
        float* op = out + j0 + n * 16 + c;
        #pragma unroll
        for (int r = 0; r < 4; ++r)
            op[(size_t)(w * 16 + kg * 4 + r) * 16384] = acc[n][r];
    }
}

extern "C" void kernel_launch(void* const* d_in, const int* in_sizes, int n_in,
                              void* d_out, int out_size, void* d_ws, size_t ws_size,
                              hipStream_t stream) {
    const float* x  = (const float*)d_in[0];
    const float* W  = (const float*)d_in[1];
    const float* A  = (const float*)d_in[2];
    const float* Bm = (const float*)d_in[3];
    float* out = (float*)d_out;

    ushort* xb = (ushort*)d_ws;                          // 64*4096*2 = 524288 B
    ushort* yb = (ushort*)((char*)d_ws + 524288);        // 64*64*2   = 8192 B

    prep_kernel<<<1024, 256, 0, stream>>>(x, A, xb, yb);
    lora_gemm<<<256, 512, 0, stream>>>(W, Bm, xb, yb, out);
}